// Round 10
// baseline (325.936 us; speedup 1.0000x reference)
//
#include <hip/hip_runtime.h>
#include <hip/hip_bf16.h>
#include <math.h>

// Gate: logits = x @ W^T ; scores = sigmoid(logits)+bias ; top-8 ; normalize *2.5
// T=16384, H=K=4096, E=256.
// fp32 GEMM via SCALED f16 2-level split, 3 products (R9: absmax 0.0):
//   x = h1 + 2^-12 h2 + r; both levels f16-normal; W guard w1=0 if |w|<2^-14.
// Round 10: occupancy fix. NT=512, 8 waves (2 wm x 4 wn), wave tile 32x32,
// 2 blocks/CU -> 4 waves/SIMD (was 2). A in regs (split on the fly), B 2-level
// double-buffered LDS (64 KiB), barrier-at-top single sync/step, grid 512.

using f16x8  = __attribute__((ext_vector_type(8))) _Float16;
using f32x16 = __attribute__((ext_vector_type(16))) float;

constexpr int E_EXPERTS = 256;
constexpr int KDIM      = 4096;
constexpr int TOPK      = 8;
constexpr float SCALE   = 2.5f;

constexpr int BM = 64, BN = 128, BK = 64, NT = 512;
constexpr int NSTEP = KDIM / BK;   // 64
constexpr float F16_MIN_NORMAL = 6.1035156e-5f;
// LDS: 2 buffers x 2 levels x [128 e][64 k] f16 = 32768 shorts = 64 KiB.
// Row = 64 shorts (128 B) = 8 chunks of 8 f16. Physical chunk pc of row e holds
// logical chunk pc ^ (e&7) -> an aligned 8-lane group of a ds_read_b128 covers
// all 8 chunk slots -> all 32 banks. gll dest LINEAR; global source pre-permuted.

__device__ __forceinline__ void load_lds16(const short* g, short* l) {
    auto gp = (const __attribute__((address_space(1))) short*)g;
    auto lp = (__attribute__((address_space(3))) short*)(uintptr_t)l;
    __builtin_amdgcn_global_load_lds(gp, lp, 16, 0, 0);
}

// One-time W split (RNE, scaled level 2, denormal guard on level 1).
__global__ void wsplit_kernel(const float* __restrict__ W, short* __restrict__ W1,
                              short* __restrict__ W2) {
    int i = blockIdx.x * 256 + threadIdx.x;   // float4 index
    float4 w = ((const float4*)W)[i];
    float v[4] = {w.x, w.y, w.z, w.w};
    short o1[4], o2[4];
#pragma unroll
    for (int j = 0; j < 4; ++j) {
        _Float16 h1 = (fabsf(v[j]) >= F16_MIN_NORMAL) ? (_Float16)v[j] : (_Float16)0.0f;
        _Float16 h2 = (_Float16)((v[j] - (float)h1) * 4096.0f);
        o1[j] = __builtin_bit_cast(short, h1);
        o2[j] = __builtin_bit_cast(short, h2);
    }
    ((short4*)W1)[i] = make_short4(o1[0], o1[1], o1[2], o1[3]);
    ((short4*)W2)[i] = make_short4(o2[0], o2[1], o2[2], o2[3]);
}

__global__ __launch_bounds__(NT, 4) void gate_gemm(
    const float* __restrict__ X,
    const short* __restrict__ W1, const short* __restrict__ W2,
    const float* __restrict__ Bias, float* __restrict__ S) {
    __shared__ short lds[32768];   // 64 KiB -> 2 blocks/CU (512 thr -> 16 waves/CU)

    const int tid  = threadIdx.x;
    const int lane = tid & 63;
    const int w    = tid >> 6;        // wave 0..7
    const int wm   = w >> 2;          // 0..1 : 32-token half
    const int wn   = w & 3;           // 0..3 : 32-expert quarter

    // Bijective XCD swizzle (grid=512): the two expert-halves of each token
    // tile are logically adjacent -> same XCD -> X fetched once from HBM.
    const int p       = blockIdx.x;
    const int cpx     = gridDim.x >> 3;              // 64
    const int logical = (p & 7) * cpx + (p >> 3);
    const int tok0 = (logical >> 1) * BM;
    const int e0   = (logical & 1) * BN;

    // ---- A (in registers): 32x32x16 operand: row = lane&31,
    //      k = ks*64 + ks4*16 + (lane>>5)*8 + j.
    const float* xa = X + (size_t)(tok0 + wm * 32 + (lane & 31)) * KDIM + (lane >> 5) * 8;

    // ---- B staging: 1024 16B-units per level per buffer; 2/thread/level.
    int bsrc[2], bdst[2];
#pragma unroll
    for (int j = 0; j < 2; ++j) {
        int f = j * 512 + tid;
        int e = f >> 3, pc = f & 7;
        int c = pc ^ (e & 7);
        bsrc[j] = (e0 + e) * KDIM + c * 8;   // + k0 at use (shorts)
        bdst[j] = f * 8;                     // + buf, lev at use; lane-linear x16B
    }

    // ---- B read offsets: e = wn*32 + (lane&31); chunk cf = ks4*2 + (lane>>5)
    int bro[4];
    {
        int e = wn * 32 + (lane & 31);
#pragma unroll
        for (int ks4 = 0; ks4 < 4; ++ks4) {
            int pc = (ks4 * 2 + (lane >> 5)) ^ (e & 7);
            bro[ks4] = e * 64 + pc * 8;
        }
    }

    auto stage = [&](int bufOff, int k0) {
#pragma unroll
        for (int j = 0; j < 2; ++j) {
            load_lds16(W1 + (size_t)bsrc[j] + k0, &lds[bufOff + bdst[j]]);
            load_lds16(W2 + (size_t)bsrc[j] + k0, &lds[bufOff + 8192 + bdst[j]]);
        }
    };

    float4 raw[4][2];   // [ks4][half] : 8 floats per 16-k chunk
    auto loadA = [&](int ks) {
#pragma unroll
        for (int ks4 = 0; ks4 < 4; ++ks4) {
            const float* s = xa + (size_t)ks * BK + ks4 * 16;
            raw[ks4][0] = *(const float4*)s;
            raw[ks4][1] = *(const float4*)(s + 4);
        }
    };

    f32x16 accM, accC;
#pragma unroll
    for (int j = 0; j < 16; ++j) { accM[j] = 0.0f; accC[j] = 0.0f; }

    // ---- prologue: issue step-0 loads; first barrier pays their latency once.
    stage(0, 0);
    loadA(0);

    int buf = 0;
    for (int ks = 0; ks < NSTEP; ++ks) {
        // Barrier AT TOP: drains loads issued a full iteration ago (free) and
        // fences the buffer this iteration's stage() will overwrite.
        __syncthreads();

        if (ks + 1 < NSTEP) stage((buf ^ 1) * 16384, (ks + 1) * BK);

        // split A(ks): scaled f16 2-level, per lane (raw still holds step ks)
        f16x8 fa1[4], fa2[4];
#pragma unroll
        for (int ks4 = 0; ks4 < 4; ++ks4) {
            float v[8] = {raw[ks4][0].x, raw[ks4][0].y, raw[ks4][0].z, raw[ks4][0].w,
                          raw[ks4][1].x, raw[ks4][1].y, raw[ks4][1].z, raw[ks4][1].w};
#pragma unroll
            for (int j = 0; j < 8; ++j) {
                _Float16 h1 = (fabsf(v[j]) >= F16_MIN_NORMAL) ? (_Float16)v[j] : (_Float16)0.0f;
                _Float16 h2 = (_Float16)((v[j] - (float)h1) * 4096.0f);
                fa1[ks4][j] = h1;
                fa2[ks4][j] = h2;
            }
        }

        if (ks + 1 < NSTEP) loadA(ks + 1);   // A prefetch -> regs (consumed next step)

        // compute: 4 chunks x 3 products of 32x32x16 f16
        const int bo = buf * 16384;
        f16x8 b1[4], b2[4];
#pragma unroll
        for (int ks4 = 0; ks4 < 4; ++ks4) {
            b1[ks4] = *(const f16x8*)&lds[bo + bro[ks4]];
            b2[ks4] = *(const f16x8*)&lds[bo + 8192 + bro[ks4]];
        }
#pragma unroll
        for (int ks4 = 0; ks4 < 4; ++ks4) {
            accM = __builtin_amdgcn_mfma_f32_32x32x16_f16(fa1[ks4], b1[ks4], accM, 0, 0, 0);
            accC = __builtin_amdgcn_mfma_f32_32x32x16_f16(fa1[ks4], b2[ks4], accC, 0, 0, 0);
            accC = __builtin_amdgcn_mfma_f32_32x32x16_f16(fa2[ks4], b1[ks4], accC, 0, 0, 0);
        }
        buf ^= 1;
    }

    // ---- epilogue: combine scales, sigmoid + bias -> scores
    // 32x32 C/D: col(expert) = lane&31, row = (reg&3) + 8*(reg>>2) + 4*(lane>>5).
    {
        const int ec = e0 + wn * 32 + (lane & 31);
        const float bv = Bias[ec];
#pragma unroll
        for (int reg = 0; reg < 16; ++reg) {
            const int tr = tok0 + wm * 32 + (reg & 3) + 8 * (reg >> 2) + 4 * (lane >> 5);
            const float logit = accM[reg] + accC[reg] * (1.0f / 4096.0f);
            S[(size_t)tr * E_EXPERTS + ec] = 1.0f / (1.0f + expf(-logit)) + bv;
        }
    }
}

// One wave per token: 256 scores, 4/lane; 8 rounds of butterfly argmax.
// Tie-break: higher value wins; equal value -> lower index (matches lax.top_k / np).
__global__ __launch_bounds__(256) void gate_topk(
    const float* __restrict__ S, float* __restrict__ outIdx,
    float* __restrict__ outW, int T) {
    const int wave = threadIdx.x >> 6;
    const int lane = threadIdx.x & 63;
    const int t    = blockIdx.x * 4 + wave;
    if (t >= T) return;

    const float* row = S + (size_t)t * E_EXPERTS;
    float v[4];
    int   idx[4];
#pragma unroll
    for (int j = 0; j < 4; ++j) {
        idx[j] = lane + 64 * j;
        v[j]   = row[idx[j]];
    }

    float tv[TOPK];
    int   ti[TOPK];
#pragma unroll
    for (int k = 0; k < TOPK; ++k) {
        float bv = v[0];
        int   bi = idx[0];
#pragma unroll
        for (int j = 1; j < 4; ++j)
            if (v[j] > bv) { bv = v[j]; bi = idx[j]; }
#pragma unroll
        for (int off = 1; off < 64; off <<= 1) {
            float ov = __shfl_xor(bv, off);
            int   oi = __shfl_xor(bi, off);
            if (ov > bv || (ov == bv && oi < bi)) { bv = ov; bi = oi; }
        }
        tv[k] = bv;
        ti[k] = bi;
#pragma unroll
        for (int j = 0; j < 4; ++j)
            if (idx[j] == bi) v[j] = -INFINITY;
    }

    float denom = 0.0f;
#pragma unroll
    for (int k = 0; k < TOPK; ++k) denom += tv[k];
    denom += 1e-20f;

#pragma unroll
    for (int k = 0; k < TOPK; ++k) {
        if (lane == k) {
            outIdx[(size_t)t * TOPK + k] = (float)ti[k];
            outW[(size_t)t * TOPK + k]   = (tv[k] / denom) * SCALE;
        }
    }
}

extern "C" void kernel_launch(void* const* d_in, const int* in_sizes, int n_in,
                              void* d_out, int out_size, void* d_ws, size_t ws_size,
                              hipStream_t stream) {
    const float* x    = (const float*)d_in[0];
    const float* w    = (const float*)d_in[1];
    const float* bias = (const float*)d_in[2];

    const int T = in_sizes[0] / KDIM;   // 16384

    float* S  = (float*)d_ws;                                        // [T][256] f32, 16 MiB
    short* W1 = (short*)((char*)d_ws + (size_t)T * E_EXPERTS * 4);   // 2 x 2 MiB f16
    short* W2 = W1 + (size_t)E_EXPERTS * KDIM;

    float* outIdx = (float*)d_out;                  // idx chunk (as float values)
    float* outW   = outIdx + (size_t)T * TOPK;      // weight chunk

    wsplit_kernel<<<(E_EXPERTS * KDIM / 4) / 256, 256, 0, stream>>>(w, W1, W2);
    gate_gemm<<<(T / BM) * (E_EXPERTS / BN), NT, 0, stream>>>(x, W1, W2, bias, S);
    gate_topk<<<T / 4, 256, 0, stream>>>(S, outIdx, outW, T);
}